// Round 4
// baseline (445.932 us; speedup 1.0000x reference)
//
#include <hip/hip_runtime.h>
#include <hip/hip_bf16.h>

#define N_V   100000
#define N_E   100000
#define NNZ_C 800000
#define HC    128
#define H_    8
#define C_    16
#define NEG   0.2f

typedef __attribute__((ext_vector_type(8))) short bf16x8;
typedef __attribute__((ext_vector_type(4))) float f32x4;

__device__ __forceinline__ short f2bf(float f) {
    unsigned u = __float_as_uint(f);
    unsigned r = (u + 0x7FFFu + ((u >> 16) & 1u)) >> 16;   // RNE
    return (short)r;
}
__device__ __forceinline__ float bf2f(unsigned short u) {
    return __uint_as_float(((unsigned)u) << 16);
}

// ---------------- W transpose to bf16: Wt[c][k] = bf16(W[k][c]) ----------------
__global__ __launch_bounds__(256) void wt_k(const float* __restrict__ W, unsigned short* __restrict__ Wt) {
    int i = blockIdx.x * 256 + threadIdx.x;
    int k = i >> 7, c = i & 127;
    Wt[c * 128 + k] = (unsigned short)f2bf(W[k * 128 + c]);
}

// ---------------- MFMA GEMM: X0b = bf16(X @ W) ----------------
__global__ __launch_bounds__(256) void gemm_mfma_k(const float* __restrict__ X,
                                                   const unsigned short* __restrict__ Wt,
                                                   unsigned short* __restrict__ X0b) {
    __shared__ unsigned long long lds[4096];   // swizzled Wt, 32 KB
    int tid = threadIdx.x;
    const unsigned long long* wt8 = (const unsigned long long*)Wt;
    for (int u = tid; u < 4096; u += 256) {
        int col = u >> 5, g = u & 31;
        lds[(col << 5) | (g ^ (col & 15))] = wt8[u];
    }
    __syncthreads();

    int wave = tid >> 6, lane = tid & 63;
    int cl = lane & 15, kq = lane >> 4;
    int base = blockIdx.x * 64 + wave * 16;
    int rowA = base + cl;
    int srcRow = (rowA < N_V) ? rowA : (N_V - 1);

    f32x4 acc[8] = {};
    const float4* X4 = (const float4*)X;

    #pragma unroll
    for (int ks = 0; ks < 4; ++ks) {
        float4 a0 = X4[(size_t)srcRow * 32 + 8 * ks + kq];
        float4 a1 = X4[(size_t)srcRow * 32 + 8 * ks + 4 + kq];
        bf16x8 af;
        af[0] = f2bf(a0.x); af[1] = f2bf(a0.y); af[2] = f2bf(a0.z); af[3] = f2bf(a0.w);
        af[4] = f2bf(a1.x); af[5] = f2bf(a1.y); af[6] = f2bf(a1.z); af[7] = f2bf(a1.w);
        int g0 = 8 * ks + kq;
        int g1 = g0 + 4;
        #pragma unroll
        for (int ct = 0; ct < 8; ++ct) {
            int col = ct * 16 + cl;
            union { unsigned long long q[2]; bf16x8 v; } bu;
            bu.q[0] = lds[(col << 5) | (g0 ^ cl)];
            bu.q[1] = lds[(col << 5) | (g1 ^ cl)];
            acc[ct] = __builtin_amdgcn_mfma_f32_16x16x32_bf16(af, bu.v, acc[ct], 0, 0, 0);
        }
    }
    int rbase = base + kq * 4;
    #pragma unroll
    for (int ct = 0; ct < 8; ++ct) {
        #pragma unroll
        for (int r = 0; r < 4; ++r) {
            int row = rbase + r;
            if (row < N_V) X0b[(size_t)row * 128 + ct * 16 + cl] = (unsigned short)f2bf(acc[ct][r]);
        }
    }
}

// ---------------- combined CSR build: histogram / scan / fill ----------------
__global__ __launch_bounds__(256) void hist2_k(const int* __restrict__ edges, const int* __restrict__ vertex,
                                               int* __restrict__ ecnt, int* __restrict__ vcnt) {
    int e = blockIdx.x * 256 + threadIdx.x;
    if (e < NNZ_C) {
        atomicAdd(&ecnt[edges[e]], 1);
        atomicAdd(&vcnt[vertex[e]], 1);
    }
}

__global__ __launch_bounds__(256) void scan1_k(const int* __restrict__ cnt, int* __restrict__ off,
                                               int* __restrict__ bsum, int L) {
    __shared__ int s[256];
    int i = blockIdx.x * 256 + threadIdx.x;
    int v = (i < L) ? cnt[i] : 0;
    s[threadIdx.x] = v;
    __syncthreads();
    for (int d = 1; d < 256; d <<= 1) {
        int t = 0;
        if (threadIdx.x >= d) t = s[threadIdx.x - d];
        __syncthreads();
        if (threadIdx.x >= d) s[threadIdx.x] += t;
        __syncthreads();
    }
    if (i <= L) off[i] = s[threadIdx.x] - v;
    if (threadIdx.x == 255) bsum[blockIdx.x] = s[255];
}

__global__ __launch_bounds__(512) void scan2_k(int* __restrict__ bsum, int nb) {
    __shared__ int s[512];
    int t = threadIdx.x;
    int v = (t < nb) ? bsum[t] : 0;
    s[t] = v;
    __syncthreads();
    for (int d = 1; d < 512; d <<= 1) {
        int tv = 0;
        if (t >= d) tv = s[t - d];
        __syncthreads();
        if (t >= d) s[t] += tv;
        __syncthreads();
    }
    if (t < nb) bsum[t] = s[t] - v;
}

__global__ __launch_bounds__(256) void scan3_k(int* __restrict__ off, const int* __restrict__ bsum,
                                               int* __restrict__ cur, int L) {
    int i = blockIdx.x * 256 + threadIdx.x;
    if (i <= L) {
        int o = off[i] + bsum[i >> 8];
        off[i] = o;
        if (i < L) cur[i] = o;
    }
}

__global__ __launch_bounds__(256) void fill2_k(const int* __restrict__ edges, const int* __restrict__ vertex,
                                               int* __restrict__ ecur, int* __restrict__ vcur,
                                               int* __restrict__ e_idx, int* __restrict__ v_idx) {
    int e = blockIdx.x * 256 + threadIdx.x;
    if (e < NNZ_C) {
        int ed = edges[e], v = vertex[e];
        int p = atomicAdd(&ecur[ed], 1);
        e_idx[p] = v;
        int q = atomicAdd(&vcur[v], 1);
        v_idx[q] = ed;
    }
}

// ---------------- edge aggregation (gather, bf16 rows) + leaky attention logits ----------------
__global__ __launch_bounds__(256) void agg_gather_k(const unsigned int* __restrict__ X0b,
                                                    const int* __restrict__ e_off,
                                                    const int* __restrict__ e_idx,
                                                    const float* __restrict__ att,
                                                    unsigned int* __restrict__ Xeb,
                                                    float* __restrict__ alpha_l) {
    int wave = (int)((blockIdx.x * 256 + threadIdx.x) >> 6);
    int lane = threadIdx.x & 63;
    if (wave >= N_E) return;
    int beg = e_off[wave], end = e_off[wave + 1];
    float2 acc = {0.f, 0.f};
    for (int i = beg; i < end; ++i) {
        int v = e_idx[i];
        unsigned int p = X0b[(size_t)v * 64 + lane];
        acc.x += bf2f((unsigned short)(p & 0xFFFF));
        acc.y += bf2f((unsigned short)(p >> 16));
    }
    float inv = 1.f / fmaxf((float)(end - beg), 1.f);
    acc.x *= inv; acc.y *= inv;
    unsigned short lo = (unsigned short)f2bf(acc.x);
    unsigned short hi = (unsigned short)f2bf(acc.y);
    Xeb[(size_t)wave * 64 + lane] = ((unsigned)hi << 16) | lo;
    // logits from the ROUNDED values so both consumers agree
    float rx = bf2f(lo), ry = bf2f(hi);
    float2 a2 = ((const float2*)att)[lane];
    float s = rx * a2.x + ry * a2.y;
    s += __shfl_xor(s, 1);
    s += __shfl_xor(s, 2);
    s += __shfl_xor(s, 4);
    if ((lane & 7) == 0) {
        s = (s >= 0.f) ? s : NEG * s;          // leaky applied once
        alpha_l[wave * 8 + (lane >> 3)] = s;
    }
}

// ---------------- fused per-vertex softmax + attention-weighted gather (bf16 rows) ----------------
__global__ __launch_bounds__(256) void out_fused_k(const unsigned int* __restrict__ Xeb,
                                                   const float* __restrict__ alpha_l,
                                                   const int* __restrict__ v_off,
                                                   const int* __restrict__ v_idx,
                                                   float* __restrict__ out) {
    int wave = (int)((blockIdx.x * 256 + threadIdx.x) >> 6);
    int lane = threadIdx.x & 63;
    if (wave >= N_V) return;
    int beg = v_off[wave], end = v_off[wave + 1];

    const float SENT = -1e30f;
    int h1 = lane & 7, s = lane >> 3;
    float m = SENT, d = 0.f;
    for (int i0 = beg; i0 < end; i0 += 8) {
        int i = i0 + s;
        float a = SENT;
        if (i < end) a = alpha_l[v_idx[i] * 8 + h1];
        float mn = fmaxf(m, a);
        d = d * __expf(m - mn) + ((i < end) ? __expf(a - mn) : 0.f);
        m = mn;
    }
    #pragma unroll
    for (int msk = 8; msk < 64; msk <<= 1) {
        float mo = __shfl_xor(m, msk);
        float dd = __shfl_xor(d, msk);
        float mn = fmaxf(m, mo);
        d = d * __expf(m - mn) + dd * __expf(mo - mn);
        m = mn;
    }
    int h = lane >> 3;
    float mh = __shfl(m, h);
    float dh = __shfl(d, h);
    float rd = 1.f / (dh + 1e-16f);

    float2 acc = {0.f, 0.f};
    for (int i = beg; i < end; ++i) {
        int ed = v_idx[i];
        float a = alpha_l[ed * 8 + h];
        float w = __expf(a - mh) * rd;
        unsigned int p = Xeb[(size_t)ed * 64 + lane];
        acc.x += bf2f((unsigned short)(p & 0xFFFF)) * w;
        acc.y += bf2f((unsigned short)(p >> 16)) * w;
    }
    ((float2*)out)[(size_t)wave * 64 + lane] = acc;
}

extern "C" void kernel_launch(void* const* d_in, const int* in_sizes, int n_in,
                              void* d_out, int out_size, void* d_ws, size_t ws_size,
                              hipStream_t stream) {
    const float* X      = (const float*)d_in[0];
    const float* W      = (const float*)d_in[1];
    const float* att    = (const float*)d_in[2];
    const int*   vertex = (const int*)d_in[3];
    const int*   edges  = (const int*)d_in[4];
    float* out = (float*)d_out;

    // -------- workspace layout (no overlays; ~63 MB total) --------
    unsigned short* X0b = (unsigned short*)d_ws;              // N*128 bf16 (25.6 MB)
    unsigned short* Xeb = X0b + (size_t)N_V * HC;             // M*128 bf16 (25.6 MB)
    int*   e_off   = (int*)(Xeb + (size_t)N_E * HC);          // M+1
    int*   ecnt    = e_off + (N_E + 1);                       // M
    int*   e_idx   = ecnt + N_E;                              // NNZ
    int*   v_off   = e_idx + NNZ_C;                           // N+1
    int*   vcnt    = v_off + (N_V + 1);                       // N
    int*   v_idx   = vcnt + N_V;                              // NNZ
    float* alpha_l = (float*)(v_idx + NNZ_C);                 // M*8
    int*   bsum    = (int*)(alpha_l + (size_t)N_E * H_);      // 512
    unsigned short* Wt = (unsigned short*)(bsum + 512);       // 128*128 bf16

    const int nbE = (N_E + 1 + 255) / 256;
    const int nbV = (N_V + 1 + 255) / 256;

    // -------- combined CSR build --------
    hipMemsetAsync(ecnt, 0, sizeof(int) * N_E, stream);
    hipMemsetAsync(vcnt, 0, sizeof(int) * N_V, stream);
    hist2_k<<<NNZ_C / 256, 256, 0, stream>>>(edges, vertex, ecnt, vcnt);
    scan1_k<<<nbE, 256, 0, stream>>>(ecnt, e_off, bsum, N_E);
    scan2_k<<<1, 512, 0, stream>>>(bsum, nbE);
    scan3_k<<<nbE, 256, 0, stream>>>(e_off, bsum, ecnt, N_E);
    scan1_k<<<nbV, 256, 0, stream>>>(vcnt, v_off, bsum, N_V);
    scan2_k<<<1, 512, 0, stream>>>(bsum, nbV);
    scan3_k<<<nbV, 256, 0, stream>>>(v_off, bsum, vcnt, N_V);
    fill2_k<<<NNZ_C / 256, 256, 0, stream>>>(edges, vertex, ecnt, vcnt, e_idx, v_idx);

    // -------- GEMM (bf16 MFMA) + edge aggregation --------
    wt_k        <<<64, 256, 0, stream>>>(W, Wt);
    gemm_mfma_k <<<(N_V + 63) / 64, 256, 0, stream>>>(X, Wt, X0b);
    agg_gather_k<<<(N_E * 64) / 256, 256, 0, stream>>>((const unsigned int*)X0b, e_off, e_idx, att, (unsigned int*)Xeb, alpha_l);

    // -------- fused softmax + output gather --------
    out_fused_k<<<(N_V * 64) / 256, 256, 0, stream>>>((const unsigned int*)Xeb, alpha_l, v_off, v_idx, out);
}